// Round 4
// baseline (138.936 us; speedup 1.0000x reference)
//
#include <hip/hip_runtime.h>

// B=2, S=2048, D=1024, H=16, HD=64. K == Q (xk = x@Wq.T, same RoPE).
// Pipeline: f32->bf16 convert -> [GEMM+RoPE -> Q bf16 [B,H,S,64]],
//           [GEMM -> V^T bf16 [B,H,64,S]] -> flash attention.
// Attn: wave-k-split. Block = 64 q-rows; wave w takes k-tiles kt%4==w.
// Q in regs; K/V frags loaded global->reg with sigma'd addresses (no LDS,
// no barriers in main loop). Swapped QK^T => in-register softmax (cvt_pk),
// defer-max. 4-way (O,m,l) merge via LDS at the end (two passes).

typedef float f32x4 __attribute__((ext_vector_type(4)));
typedef short s16x8 __attribute__((ext_vector_type(8)));

__device__ inline unsigned short f2bf(float f) {
  union { float f; unsigned u; } v; v.f = f;
  unsigned r = v.u + 0x7FFFu + ((v.u >> 16) & 1u);
  return (unsigned short)(r >> 16);
}

__global__ __launch_bounds__(256) void convert_bf16(
    const float* __restrict__ in, unsigned short* __restrict__ out, int n4) {
  int i = blockIdx.x * blockDim.x + threadIdx.x;
  if (i < n4) {
    float4 v = ((const float4*)in)[i];
    ushort4 o;
    o.x = f2bf(v.x); o.y = f2bf(v.y); o.z = f2bf(v.z); o.w = f2bf(v.w);
    ((ushort4*)out)[i] = o;
  }
}

// out[m][n] = sum_k A[m][k] * W[n][k];  M=4096, N=1024, K=1024 (bf16 in, f32 acc)
// IS_Q: fuse RoPE, write Q[b][h][s][hd] ; else write V^T[b][h][hd][s]
template <int IS_Q>
__global__ __launch_bounds__(256) void qv_gemm(
    const unsigned short* __restrict__ A, const unsigned short* __restrict__ W,
    const float* __restrict__ cosT, const float* __restrict__ sinT,
    unsigned short* __restrict__ Out) {
  __shared__ unsigned short As[128][72];
  __shared__ unsigned short Bs[128][72];
  const int K = 1024;
  int tid = threadIdx.x;
  int bm = blockIdx.x & 31, bn = blockIdx.x >> 5;
  int w = tid >> 6, lane = tid & 63, lr = lane & 15, lg = lane >> 4;
  int wm = w >> 1, wn = w & 1;
  f32x4 acc[4][4] = {};

  for (int kt = 0; kt < K; kt += 64) {
#pragma unroll
    for (int i = 0; i < 4; ++i) {
      int c = tid + 256 * i;
      int r = c >> 3, cc = c & 7;
      *(s16x8*)&As[r][cc * 8] = *(const s16x8*)&A[(bm * 128 + r) * K + kt + cc * 8];
      *(s16x8*)&Bs[r][cc * 8] = *(const s16x8*)&W[(bn * 128 + r) * K + kt + cc * 8];
    }
    __syncthreads();
    s16x8 af[4][2], bfr[4][2];
#pragma unroll
    for (int mf = 0; mf < 4; ++mf)
#pragma unroll
      for (int kk = 0; kk < 2; ++kk)
        af[mf][kk] = *(const s16x8*)&As[wm * 64 + mf * 16 + lr][kk * 32 + lg * 8];
#pragma unroll
    for (int nf = 0; nf < 4; ++nf)
#pragma unroll
      for (int kk = 0; kk < 2; ++kk)
        bfr[nf][kk] = *(const s16x8*)&Bs[wn * 64 + nf * 16 + lr][kk * 32 + lg * 8];
#pragma unroll
    for (int mf = 0; mf < 4; ++mf)
#pragma unroll
      for (int nf = 0; nf < 4; ++nf)
#pragma unroll
        for (int kk = 0; kk < 2; ++kk)
          acc[mf][nf] = __builtin_amdgcn_mfma_f32_16x16x32_bf16(
              af[mf][kk], bfr[nf][kk], acc[mf][nf], 0, 0, 0);
    __syncthreads();
  }

  int mBase = bm * 128 + wm * 64;
  int nBase = bn * 128 + wn * 64;
#pragma unroll
  for (int mf = 0; mf < 4; ++mf)
#pragma unroll
    for (int j = 0; j < 4; ++j) {
      int m = mBase + mf * 16 + 4 * lg + j;
      int b = m >> 11, s = m & 2047;
      if (IS_Q) {
#pragma unroll
        for (int nf = 0; nf < 4; ++nf) {
          int col = nBase + nf * 16 + lr;
          int h = col >> 6, hd = col & 63;
          float self = acc[mf][nf][j];
          float part = (nf < 2) ? -acc[mf][nf + 2][j] : acc[mf][nf - 2][j];
          float val = self * cosT[s * 64 + hd] + part * sinT[s * 64 + hd];
          Out[(((b * 16 + h) * 2048 + s) << 6) + hd] = f2bf(val);
        }
      } else {
#pragma unroll
        for (int nf = 0; nf < 4; ++nf) {
          int col = nBase + nf * 16 + lr;
          int h = col >> 6, hd = col & 63;
          Out[((b * 16 + h) * 64 + hd) * 2048 + s] = f2bf(acc[mf][nf][j]);
        }
      }
    }
}

// grid 1024: fid -> XCD-chunked (bh) x qt-descending (LPT dispatch).
__global__ __launch_bounds__(256, 2) void attn(
    const unsigned short* __restrict__ Qb,  // [32][2048][64]
    const unsigned short* __restrict__ Vt,  // [32][64][2048]
    float* __restrict__ out) {              // [2][2048][1024]
  __shared__ float Ol[4][2][4][16][17];
  __shared__ float Mm[4][4][16];
  __shared__ float Ll[4][4][16];
  const float SC = 0.125f * 1.44269504088896f;  // scale * log2(e)
  const float THR = 44.0f;                      // ~= 8 / SC
  int tid = threadIdx.x;
  int fid = blockIdx.x;
  int bh = 4 * (fid & 7) + ((fid >> 3) & 3);
  int qt = 31 - (fid >> 5);
  int w = tid >> 6, lane = tid & 63, lr = lane & 15, lg = lane >> 4;
  int q0 = qt * 64;
  const unsigned short* Qh = Qb + bh * (2048 * 64);
  const unsigned short* Vh = Vt + bh * (64 * 2048);

  // Q fragments (all 64 q-rows, B-operand), live whole kernel: 32 VGPR
  s16x8 aq[4][2];
#pragma unroll
  for (int qs = 0; qs < 4; ++qs)
#pragma unroll
    for (int kk = 0; kk < 2; ++kk)
      aq[qs][kk] = *(const s16x8*)&Qh[(q0 + 16 * qs + lr) * 64 + kk * 32 + lg * 8];

  // sigma'd K row: A-row lr holds kcol crow(lr)+off[nf] so that C/D row
  // 4lg+j lands at kcol 8lg+j+off[nf] (P packs contiguously via cvt_pk).
  int crow = 8 * (lr >> 2) + (lr & 3);

  f32x4 o[4][4] = {};
  float m_[4], l_[4];
#pragma unroll
  for (int qs = 0; qs < 4; ++qs) { m_[qs] = -1e30f; l_[qs] = 0.f; }

  auto loadK = [&](s16x8 (&kf)[4][2], int kt) {
    int k0 = kt * 64;
#pragma unroll
    for (int nf = 0; nf < 4; ++nf) {
      int kc = k0 + crow + 4 * (nf & 1) + 32 * (nf >> 1);
#pragma unroll
      for (int kk = 0; kk < 2; ++kk)
        kf[nf][kk] = *(const s16x8*)&Qh[kc * 64 + kk * 32 + lg * 8];
    }
  };

  auto process = [&](const s16x8 (&kf)[4][2], int kt) {
    int k0 = kt * 64;
    // V frags for this tile (B-operand), issued before QK -> latency hidden
    s16x8 vf[4][2];
#pragma unroll
    for (int nf = 0; nf < 4; ++nf)
#pragma unroll
      for (int kk = 0; kk < 2; ++kk)
        vf[nf][kk] = *(const s16x8*)&Vh[(16 * nf + lr) * 2048 + k0 + kk * 32 + lg * 8];

    f32x4 sa[4][4];
#pragma unroll
    for (int qs = 0; qs < 4; ++qs)
#pragma unroll
      for (int nf = 0; nf < 4; ++nf) sa[qs][nf] = (f32x4){0.f, 0.f, 0.f, 0.f};
#pragma unroll
    for (int kk = 0; kk < 2; ++kk)
#pragma unroll
      for (int nf = 0; nf < 4; ++nf)
#pragma unroll
        for (int qs = 0; qs < 4; ++qs)
          sa[qs][nf] = __builtin_amdgcn_mfma_f32_16x16x32_bf16(
              kf[nf][kk], aq[qs][kk], sa[qs][nf], 0, 0, 0);
    // sa[qs][nf][j] = S[kcol = k0+8lg+j+off(nf)][q = q0+16qs+lr]
    if (kt == qt) {
#pragma unroll
      for (int qs = 0; qs < 4; ++qs) {
        int qglob = q0 + 16 * qs + lr;
#pragma unroll
        for (int nf = 0; nf < 4; ++nf) {
          int kc = k0 + 8 * lg + 4 * (nf & 1) + 32 * (nf >> 1);
#pragma unroll
          for (int j = 0; j < 4; ++j)
            if (kc + j > qglob) sa[qs][nf][j] = -3e38f;
        }
      }
    }
    float tm[4];
    float worst = -3e38f;
#pragma unroll
    for (int qs = 0; qs < 4; ++qs) {
      float t = sa[qs][0][0];
#pragma unroll
      for (int nf = 0; nf < 4; ++nf)
#pragma unroll
        for (int j = 0; j < 4; ++j) t = fmaxf(t, sa[qs][nf][j]);
      tm[qs] = t;
      worst = fmaxf(worst, t - m_[qs]);
    }
    if (!__all(worst <= THR)) {  // rare after first tile
#pragma unroll
      for (int qs = 0; qs < 4; ++qs) {
        float rm = fmaxf(tm[qs], __shfl_xor(tm[qs], 16));
        rm = fmaxf(rm, __shfl_xor(rm, 32));
        float mn = fmaxf(m_[qs], rm);
        float alpha = exp2f((m_[qs] - mn) * SC);
        m_[qs] = mn; l_[qs] *= alpha;
#pragma unroll
        for (int j = 0; j < 4; ++j) {
          float aj = __shfl(alpha, 4 * lg + j);
#pragma unroll
          for (int nf = 0; nf < 4; ++nf) o[qs][nf][j] *= aj;
        }
      }
    }
#pragma unroll
    for (int qs = 0; qs < 4; ++qs) {
      float msc = m_[qs] * SC;
      unsigned cpk[8];
#pragma unroll
      for (int nf = 0; nf < 4; ++nf) {
        float p0 = exp2f(fmaf(sa[qs][nf][0], SC, -msc));
        float p1 = exp2f(fmaf(sa[qs][nf][1], SC, -msc));
        float p2 = exp2f(fmaf(sa[qs][nf][2], SC, -msc));
        float p3 = exp2f(fmaf(sa[qs][nf][3], SC, -msc));
        l_[qs] += (p0 + p1) + (p2 + p3);
        unsigned r0, r1;
        asm("v_cvt_pk_bf16_f32 %0, %1, %2" : "=v"(r0) : "v"(p0), "v"(p1));
        asm("v_cvt_pk_bf16_f32 %0, %1, %2" : "=v"(r1) : "v"(p2), "v"(p3));
        cpk[nf * 2] = r0; cpk[nf * 2 + 1] = r1;
      }
#pragma unroll
      for (int kk = 0; kk < 2; ++kk) {
        union { unsigned u[4]; s16x8 v; } pa;
        pa.u[0] = cpk[4 * kk + 0]; pa.u[1] = cpk[4 * kk + 1];
        pa.u[2] = cpk[4 * kk + 2]; pa.u[3] = cpk[4 * kk + 3];
#pragma unroll
        for (int nf = 0; nf < 4; ++nf)
          o[qs][nf] = __builtin_amdgcn_mfma_f32_16x16x32_bf16(
              pa.v, vf[nf][kk], o[qs][nf], 0, 0, 0);
      }
    }
  };

  // main loop: wave-private k-tiles kt = w, w+4, ...  A/B pipelined K loads
  {
    s16x8 kfA[4][2], kfB[4][2];
    int kt = w;
    if (kt <= qt) {
      loadK(kfA, kt);
      while (true) {
        int ktn = kt + 4;
        if (ktn <= qt) loadK(kfB, ktn);
        process(kfA, kt);
        if (ktn > qt) break;
        kt = ktn; ktn += 4;
        if (ktn <= qt) loadK(kfA, ktn);
        process(kfB, kt);
        if (ktn > qt) break;
        kt = ktn;
      }
    }
  }

  // reduce l over lg groups (row sum for this wave's k-subset)
#pragma unroll
  for (int qs = 0; qs < 4; ++qs) {
    float t = l_[qs];
    t += __shfl_xor(t, 16); t += __shfl_xor(t, 32);
    l_[qs] = t;
  }
  if (lg == 0) {
#pragma unroll
    for (int qs = 0; qs < 4; ++qs) { Mm[w][qs][lr] = m_[qs]; Ll[w][qs][lr] = l_[qs]; }
  }

  int b = bh >> 4, h = bh & 15;
#pragma unroll
  for (int p = 0; p < 2; ++p) {
    if (p) __syncthreads();  // pass-0 reads done before overwrite
#pragma unroll
    for (int q2 = 0; q2 < 2; ++q2) {
      int qs = 2 * p + q2;
#pragma unroll
      for (int nf = 0; nf < 4; ++nf)
#pragma unroll
        for (int j = 0; j < 4; ++j)
          Ol[w][q2][nf][4 * lg + j][lr] = o[qs][nf][j];
    }
    __syncthreads();
    // wave w merges (qsub = 2p + (w&1), nf-half = w>>1)
    int qst = 2 * p + (w & 1);
    int nf0 = 2 * (w >> 1);
#pragma unroll
    for (int j = 0; j < 4; ++j) {
      int r = 4 * lg + j;
      float mv0 = Mm[0][qst][r], mv1 = Mm[1][qst][r];
      float mv2 = Mm[2][qst][r], mv3 = Mm[3][qst][r];
      float ms = fmaxf(fmaxf(mv0, mv1), fmaxf(mv2, mv3));
      float a0 = exp2f((mv0 - ms) * SC), a1 = exp2f((mv1 - ms) * SC);
      float a2 = exp2f((mv2 - ms) * SC), a3 = exp2f((mv3 - ms) * SC);
      float ls = a0 * Ll[0][qst][r] + a1 * Ll[1][qst][r] +
                 a2 * Ll[2][qst][r] + a3 * Ll[3][qst][r];
      float inv = 1.0f / ls;
      int q2 = qst & 1;
#pragma unroll
      for (int nn = 0; nn < 2; ++nn) {
        int nf = nf0 + nn;
        float ov = a0 * Ol[0][q2][nf][r][lr] + a1 * Ol[1][q2][nf][r][lr] +
                   a2 * Ol[2][q2][nf][r][lr] + a3 * Ol[3][q2][nf][r][lr];
        out[(b * 2048 + q0 + 16 * qst + r) * 1024 + h * 64 + nf * 16 + lr] = ov * inv;
      }
    }
  }
}

extern "C" void kernel_launch(void* const* d_in, const int* in_sizes, int n_in,
                              void* d_out, int out_size, void* d_ws, size_t ws_size,
                              hipStream_t stream) {
  const float* x = (const float*)d_in[0];
  const float* Wq = (const float*)d_in[1];
  const float* Wv = (const float*)d_in[2];
  const float* cosT = (const float*)d_in[3];
  const float* sinT = (const float*)d_in[4];
  float* out = (float*)d_out;

  unsigned short* xb = (unsigned short*)d_ws;        // 4M elems
  unsigned short* wqb = xb + 4 * 1024 * 1024;        // 1M
  unsigned short* wvb = wqb + 1024 * 1024;           // 1M
  unsigned short* Qb = wvb + 1024 * 1024;            // 4M (post-RoPE Q == K)
  unsigned short* Vtb = Qb + 4 * 1024 * 1024;        // 4M (V transposed)

  convert_bf16<<<4096, 256, 0, stream>>>(x, xb, 1048576);
  convert_bf16<<<1024, 256, 0, stream>>>(Wq, wqb, 262144);
  convert_bf16<<<1024, 256, 0, stream>>>(Wv, wvb, 262144);

  qv_gemm<1><<<256, 256, 0, stream>>>(xb, wqb, cosT, sinT, Qb);
  qv_gemm<0><<<256, 256, 0, stream>>>(xb, wvb, cosT, sinT, Vtb);

  attn<<<1024, 256, 0, stream>>>(Qb, Vtb, out);
}

// Round 5
// 79.595 us; speedup vs baseline: 1.7455x; 1.7455x over previous
//
#include <hip/hip_runtime.h>

// B=2, S=2048, D=1024, H=16, HD=64. K == Q (xk = x@Wq.T, same RoPE).
// Pipeline: fused f32->bf16 convert -> [GEMM+RoPE -> Q bf16 [B,H,S,64]],
//           [GEMM -> V^T bf16 [B,H,64,S]] -> flash attention.
// All staging via global_load_lds width-16 (linear LDS dest, permutation and
// XOR bank-swizzle folded into per-lane global SOURCE address; same XOR on
// LDS reads). Attn: block = 64 q-rows, 2 k-tiles/barrier; wave = (q-half,
// tile-parity); swapped QK^T -> in-register softmax (cvt_pk), defer-max;
// pairwise (m,l,O) merge via LDS at the end.

typedef float f32x4 __attribute__((ext_vector_type(4)));
typedef short s16x8 __attribute__((ext_vector_type(8)));

__device__ inline unsigned short f2bf(float f) {
  union { float f; unsigned u; } v; v.f = f;
  unsigned r = v.u + 0x7FFFu + ((v.u >> 16) & 1u);
  return (unsigned short)(r >> 16);
}

__device__ inline void gload16(const unsigned short* g, unsigned short* l) {
  __builtin_amdgcn_global_load_lds(
      (const __attribute__((address_space(1))) unsigned int*)g,
      (__attribute__((address_space(3))) unsigned int*)l, 16, 0, 0);
}

__global__ __launch_bounds__(256) void convert_all(
    const float* __restrict__ x, const float* __restrict__ wq,
    const float* __restrict__ wv, unsigned short* __restrict__ xb,
    unsigned short* __restrict__ wqb, unsigned short* __restrict__ wvb) {
  int i = blockIdx.x * 256 + threadIdx.x;
  const float* src; unsigned short* dst; int off;
  if (i < 1048576) { src = x; dst = xb; off = i; }
  else if (i < 1310720) { src = wq; dst = wqb; off = i - 1048576; }
  else { src = wv; dst = wvb; off = i - 1310720; }
  float4 v = ((const float4*)src)[off];
  ushort4 o;
  o.x = f2bf(v.x); o.y = f2bf(v.y); o.z = f2bf(v.z); o.w = f2bf(v.w);
  ((ushort4*)dst)[off] = o;
}

// out[m][n] = sum_k A[m][k]*W[n][k]; M=4096, N=1024, K=1024. bf16 in, f32 acc.
// Staging: global_load_lds, dbuf, XOR-swizzled (source-side + read-side).
// IS_Q: fuse RoPE, write Q[b][h][s][hd]; else write V^T[b][h][hd][s].
template <int IS_Q>
__global__ __launch_bounds__(256, 2) void qv_gemm(
    const unsigned short* __restrict__ A, const unsigned short* __restrict__ W,
    const float* __restrict__ cosT, const float* __restrict__ sinT,
    unsigned short* __restrict__ Out) {
  __shared__ unsigned short GS[2][2][128][64];  // [buf][A/B][row][col] 64KB
  int tid = threadIdx.x;
  int bm = blockIdx.x & 31, bn = blockIdx.x >> 5;
  int w = tid >> 6, lane = tid & 63, lr = lane & 15, lg = lane >> 4;
  int wm = w >> 1, wn = w & 1;
  int l8 = lane >> 3, l7 = lane & 7;
  f32x4 acc[4][4] = {};

  const unsigned short* srcbase =
      (w < 2) ? (A + bm * 128 * 1024) : (W + bn * 128 * 1024);
  int ab = w >> 1;

  auto stage = [&](int step) {
    int buf = step & 1, kt = step * 64;
#pragma unroll
    for (int i = 0; i < 8; ++i) {
      int rgrp = (w & 1) * 8 + i;
      int u = rgrp * 8 + l8;
      int ch = l7 ^ (u & 7);
      gload16(srcbase + u * 1024 + kt + ch * 8,
              (unsigned short*)&GS[buf][ab][rgrp * 8][0]);
    }
  };

  stage(0);
  for (int step = 0; step < 16; ++step) {
    int buf = step & 1;
    asm volatile("s_waitcnt vmcnt(0)" ::: "memory");
    __syncthreads();
    if (step + 1 < 16) stage(step + 1);
    s16x8 af[4][2], bfr[4][2];
#pragma unroll
    for (int mf = 0; mf < 4; ++mf)
#pragma unroll
      for (int kk = 0; kk < 2; ++kk)
        af[mf][kk] = *(const s16x8*)
            &GS[buf][0][wm * 64 + mf * 16 + lr][((kk * 4 + lg) ^ (lr & 7)) * 8];
#pragma unroll
    for (int nf = 0; nf < 4; ++nf)
#pragma unroll
      for (int kk = 0; kk < 2; ++kk)
        bfr[nf][kk] = *(const s16x8*)
            &GS[buf][1][wn * 64 + nf * 16 + lr][((kk * 4 + lg) ^ (lr & 7)) * 8];
#pragma unroll
    for (int mf = 0; mf < 4; ++mf)
#pragma unroll
      for (int nf = 0; nf < 4; ++nf)
#pragma unroll
        for (int kk = 0; kk < 2; ++kk)
          acc[mf][nf] = __builtin_amdgcn_mfma_f32_16x16x32_bf16(
              af[mf][kk], bfr[nf][kk], acc[mf][nf], 0, 0, 0);
  }

  int mBase = bm * 128 + wm * 64;
  int nBase = bn * 128 + wn * 64;
#pragma unroll
  for (int mf = 0; mf < 4; ++mf)
#pragma unroll
    for (int j = 0; j < 4; ++j) {
      int m = mBase + mf * 16 + 4 * lg + j;
      int b = m >> 11, s = m & 2047;
      if (IS_Q) {
#pragma unroll
        for (int nf = 0; nf < 4; ++nf) {
          int col = nBase + nf * 16 + lr;
          int h = col >> 6, hd = col & 63;
          float self = acc[mf][nf][j];
          float part = (nf < 2) ? -acc[mf][nf + 2][j] : acc[mf][nf - 2][j];
          float val = self * cosT[s * 64 + hd] + part * sinT[s * 64 + hd];
          Out[(((b * 16 + h) * 2048 + s) << 6) + hd] = f2bf(val);
        }
      } else {
#pragma unroll
        for (int nf = 0; nf < 4; ++nf) {
          int col = nBase + nf * 16 + lr;
          int h = col >> 6, hd = col & 63;
          Out[((b * 16 + h) * 64 + hd) * 2048 + s] = f2bf(acc[mf][nf][j]);
        }
      }
    }
}

// Flash attention. grid 1024: fid -> XCD-chunked bh, qt descending (LPT).
// Block = 64 q-rows; 2 k-tiles staged per barrier (DMA, dbuf);
// wave = (q-half = w>>1, tile-parity = w&1). Swapped QK^T, sigma'd K rows
// (folded into DMA source), XOR bank swizzle on rows. Pairwise merge at end.
__global__ __launch_bounds__(256, 2) void attn(
    const unsigned short* __restrict__ Qb,  // [32][2048][64]
    const unsigned short* __restrict__ Vt,  // [32][64][2048]
    float* __restrict__ out) {              // [2][2048][1024]
  __shared__ unsigned short SM[2][2][2][64][64];  // [buf][K/V][tile][row][col]
  const float SC = 0.125f * 1.44269504088896f;    // scale * log2(e)
  const float THR = 44.0f;                        // ~= 8 / SC
  int tid = threadIdx.x;
  int fid = blockIdx.x;
  int bh = 4 * (fid & 7) + ((fid >> 3) & 3);
  int qt = 31 - (fid >> 5);
  int w = tid >> 6, lane = tid & 63, lr = lane & 15, lg = lane >> 4;
  int l8 = lane >> 3, l7 = lane & 7;
  int q0 = qt * 64, qh = w >> 1, par = w & 1;
  const unsigned short* Qh = Qb + bh * (2048 * 64);
  const unsigned short* Vh = Vt + bh * (64 * 2048);

  s16x8 aq[2][2];
#pragma unroll
  for (int qs = 0; qs < 2; ++qs)
#pragma unroll
    for (int kk = 0; kk < 2; ++kk)
      aq[qs][kk] =
          *(const s16x8*)&Qh[(q0 + qh * 32 + 16 * qs + lr) * 64 + kk * 32 + lg * 8];

  f32x4 o[2][4] = {};
  float m_[2] = {-1e30f, -1e30f}, l_[2] = {0.f, 0.f};

  // wave w stages: w0 -> K tile0, w1 -> K tile1, w2 -> V tile0, w3 -> V tile1
  auto stage = [&](int ss) {
    int buf = ss & 1, k0 = ss * 128;
#pragma unroll
    for (int i = 0; i < 8; ++i) {
      int u = i * 8 + l8;
      int ch = l7 ^ (u & 7);
      const unsigned short* src;
      if (w < 2) {
        // ginv: LDS row u holds global kcol ginv(u) (sigma from round 3)
        int g = (u & 0x23) | (((u >> 4) & 1) << 2) | (((u >> 3) & 1) << 4) |
                (((u >> 2) & 1) << 3);
        src = Qh + (k0 + par * 64 + g) * 64 + ch * 8;
      } else {
        src = Vh + u * 2048 + k0 + par * 64 + ch * 8;
      }
      gload16(src, (unsigned short*)&SM[buf][w >> 1][par][i * 8][0]);
    }
  };

  int nss = (qt >> 1) + 1;
  stage(0);
  for (int ss = 0; ss < nss; ++ss) {
    int buf = ss & 1;
    asm volatile("s_waitcnt vmcnt(0)" ::: "memory");
    __syncthreads();
    if (ss + 1 < nss) stage(ss + 1);
    int kt = 2 * ss + par;
    if (kt <= qt) {
      s16x8 kf[4][2];
#pragma unroll
      for (int nf = 0; nf < 4; ++nf)
#pragma unroll
        for (int kk = 0; kk < 2; ++kk)
          kf[nf][kk] = *(const s16x8*)
              &SM[buf][0][par][nf * 16 + lr][((kk * 4 + lg) ^ (lr & 7)) * 8];
      f32x4 sa[2][4];
#pragma unroll
      for (int qs = 0; qs < 2; ++qs)
#pragma unroll
        for (int nf = 0; nf < 4; ++nf) sa[qs][nf] = (f32x4){0.f, 0.f, 0.f, 0.f};
#pragma unroll
      for (int kk = 0; kk < 2; ++kk)
#pragma unroll
        for (int nf = 0; nf < 4; ++nf)
#pragma unroll
          for (int qs = 0; qs < 2; ++qs)
            sa[qs][nf] = __builtin_amdgcn_mfma_f32_16x16x32_bf16(
                kf[nf][kk], aq[qs][kk], sa[qs][nf], 0, 0, 0);
      // sa[qs][nf][j] = S[kcol = kt*64+8lg+j+{0,4,32,36}[nf]][q = 16qs+lr]
      if (kt == qt) {
#pragma unroll
        for (int qs = 0; qs < 2; ++qs) {
          int qglob = q0 + qh * 32 + 16 * qs + lr;
#pragma unroll
          for (int nf = 0; nf < 4; ++nf) {
            int kc = kt * 64 + 8 * lg + 4 * (nf & 1) + 32 * (nf >> 1);
#pragma unroll
            for (int j = 0; j < 4; ++j)
              if (kc + j > qglob) sa[qs][nf][j] = -3e38f;
          }
        }
      }
      float tm[2];
      float worst = -3e38f;
#pragma unroll
      for (int qs = 0; qs < 2; ++qs) {
        float t = sa[qs][0][0];
#pragma unroll
        for (int nf = 0; nf < 4; ++nf)
#pragma unroll
          for (int j = 0; j < 4; ++j) t = fmaxf(t, sa[qs][nf][j]);
        tm[qs] = t;
        worst = fmaxf(worst, t - m_[qs]);
      }
      if (!__all(worst <= THR)) {  // rare after first tile
#pragma unroll
        for (int qs = 0; qs < 2; ++qs) {
          float rm = fmaxf(tm[qs], __shfl_xor(tm[qs], 16));
          rm = fmaxf(rm, __shfl_xor(rm, 32));
          float mn = fmaxf(m_[qs], rm);
          float alpha = exp2f((m_[qs] - mn) * SC);
          m_[qs] = mn; l_[qs] *= alpha;
#pragma unroll
          for (int j = 0; j < 4; ++j) {
            float aj = __shfl(alpha, 4 * lg + j);
#pragma unroll
            for (int nf = 0; nf < 4; ++nf) o[qs][nf][j] *= aj;
          }
        }
      }
      unsigned cpk[2][8];
#pragma unroll
      for (int qs = 0; qs < 2; ++qs) {
        float msc = m_[qs] * SC;
#pragma unroll
        for (int nf = 0; nf < 4; ++nf) {
          float p0 = exp2f(fmaf(sa[qs][nf][0], SC, -msc));
          float p1 = exp2f(fmaf(sa[qs][nf][1], SC, -msc));
          float p2 = exp2f(fmaf(sa[qs][nf][2], SC, -msc));
          float p3 = exp2f(fmaf(sa[qs][nf][3], SC, -msc));
          l_[qs] += (p0 + p1) + (p2 + p3);
          unsigned r0, r1;
          asm("v_cvt_pk_bf16_f32 %0, %1, %2" : "=v"(r0) : "v"(p0), "v"(p1));
          asm("v_cvt_pk_bf16_f32 %0, %1, %2" : "=v"(r1) : "v"(p2), "v"(p3));
          cpk[qs][nf * 2] = r0; cpk[qs][nf * 2 + 1] = r1;
        }
      }
      s16x8 pav[2][2];
#pragma unroll
      for (int qs = 0; qs < 2; ++qs)
#pragma unroll
        for (int kk = 0; kk < 2; ++kk) {
          union { unsigned u[4]; s16x8 v; } pa;
          pa.u[0] = cpk[qs][4 * kk + 0]; pa.u[1] = cpk[qs][4 * kk + 1];
          pa.u[2] = cpk[qs][4 * kk + 2]; pa.u[3] = cpk[qs][4 * kk + 3];
          pav[qs][kk] = pa.v;
        }
#pragma unroll
      for (int kk = 0; kk < 2; ++kk)
#pragma unroll
        for (int nf = 0; nf < 4; ++nf) {
          s16x8 vf = *(const s16x8*)
              &SM[buf][1][par][nf * 16 + lr][((kk * 4 + lg) ^ (lr & 7)) * 8];
#pragma unroll
          for (int qs = 0; qs < 2; ++qs)
            o[qs][nf] = __builtin_amdgcn_mfma_f32_16x16x32_bf16(
                pav[qs][kk], vf, o[qs][nf], 0, 0, 0);
        }
    }
  }

  // pairwise merge: waves (2p, 2p+1) share q-rows; odd writes, even merges
  __syncthreads();
  float* MB = (float*)SM;
  float* ML = MB + 4352;  // 2*2*4*16*17 floats of O, then m/l
  int pair = qh;
#pragma unroll
  for (int qs = 0; qs < 2; ++qs) {
    float t = l_[qs];
    t += __shfl_xor(t, 16); t += __shfl_xor(t, 32);
    l_[qs] = t;
  }
  if (par) {
#pragma unroll
    for (int qs = 0; qs < 2; ++qs) {
#pragma unroll
      for (int nf = 0; nf < 4; ++nf)
#pragma unroll
        for (int j = 0; j < 4; ++j)
          MB[(((pair * 2 + qs) * 4 + nf) * 16 + 4 * lg + j) * 17 + lr] = o[qs][nf][j];
      if (lg == 0) {
        ML[((pair * 2 + qs) * 2 + 0) * 16 + lr] = m_[qs];
        ML[((pair * 2 + qs) * 2 + 1) * 16 + lr] = l_[qs];
      }
    }
  }
  __syncthreads();
  if (!par) {
    int b = bh >> 4, h = bh & 15;
#pragma unroll
    for (int qs = 0; qs < 2; ++qs) {
      float m1 = ML[((pair * 2 + qs) * 2 + 0) * 16 + lr];
      float l1 = ML[((pair * 2 + qs) * 2 + 1) * 16 + lr];
      float ms = fmaxf(m_[qs], m1);
      float a0 = exp2f((m_[qs] - ms) * SC), a1 = exp2f((m1 - ms) * SC);
      float inv = 1.0f / (a0 * l_[qs] + a1 * l1);
#pragma unroll
      for (int j = 0; j < 4; ++j) {
        float c0 = __shfl(a0 * inv, 4 * lg + j);
        float c1 = __shfl(a1 * inv, 4 * lg + j);
#pragma unroll
        for (int nf = 0; nf < 4; ++nf) {
          float o1 = MB[(((pair * 2 + qs) * 4 + nf) * 16 + 4 * lg + j) * 17 + lr];
          int q = q0 + pair * 32 + 16 * qs + 4 * lg + j;
          out[(b * 2048 + q) * 1024 + h * 64 + nf * 16 + lr] =
              c0 * o[qs][nf][j] + c1 * o1;
        }
      }
    }
  }
}

extern "C" void kernel_launch(void* const* d_in, const int* in_sizes, int n_in,
                              void* d_out, int out_size, void* d_ws, size_t ws_size,
                              hipStream_t stream) {
  const float* x = (const float*)d_in[0];
  const float* Wq = (const float*)d_in[1];
  const float* Wv = (const float*)d_in[2];
  const float* cosT = (const float*)d_in[3];
  const float* sinT = (const float*)d_in[4];
  float* out = (float*)d_out;

  unsigned short* xb = (unsigned short*)d_ws;        // 4M elems
  unsigned short* wqb = xb + 4 * 1024 * 1024;        // 1M
  unsigned short* wvb = wqb + 1024 * 1024;           // 1M
  unsigned short* Qb = wvb + 1024 * 1024;            // 4M (post-RoPE Q == K)
  unsigned short* Vtb = Qb + 4 * 1024 * 1024;        // 4M (V transposed)

  convert_all<<<6144, 256, 0, stream>>>(x, Wq, Wv, xb, wqb, wvb);

  qv_gemm<1><<<256, 256, 0, stream>>>(xb, wqb, cosT, sinT, Qb);
  qv_gemm<0><<<256, 256, 0, stream>>>(xb, wvb, cosT, sinT, Vtb);

  attn<<<1024, 256, 0, stream>>>(Qb, Vtb, out);
}

// Round 6
// 66.285 us; speedup vs baseline: 2.0960x; 1.2008x over previous
//
#include <hip/hip_runtime.h>

// B=2, S=2048, D=1024, H=16, HD=64. K == Q (xk = x@Wq.T, same RoPE).
// Pipeline: fused f32->bf16 convert -> one merged GEMM kernel:
//   [x@Wq.T + RoPE -> Kf frag-layout], [x@Wv.T -> Vf frag-layout]
// -> flash attention with NO LDS staging / NO barriers in the main loop:
//   K/V fragments are stored in exact MFMA-fragment order, so each frag load
//   is a fully-coalesced global_load_dwordx4 (base + lane*16B), L2-resident.
// Frag layout: F[bh][kt][nf][kk][lane][8 shorts];
//   Kf[...][lane=(lg,lr)] = K[kt*64 + crow(lr) + 4(nf&1) + 32(nf>>1)][kk*32+lg*8..]
//   Vf[...][lane=(lg,lr)] = V[kt*64 + kk*32 + lg*8..][16nf + lr]   (V^T frags)
// crow(lr) = 8*(lr>>2)+(lr&3): makes swapped-QK^T output land in PV-A order.

typedef float f32x4 __attribute__((ext_vector_type(4)));
typedef short s16x8 __attribute__((ext_vector_type(8)));

__device__ inline unsigned short f2bf(float f) {
  union { float f; unsigned u; } v; v.f = f;
  unsigned r = v.u + 0x7FFFu + ((v.u >> 16) & 1u);
  return (unsigned short)(r >> 16);
}

__device__ inline void gload16(const unsigned short* g, unsigned short* l) {
  __builtin_amdgcn_global_load_lds(
      (const __attribute__((address_space(1))) unsigned int*)g,
      (__attribute__((address_space(3))) unsigned int*)l, 16, 0, 0);
}

__global__ __launch_bounds__(256) void convert_all(
    const float* __restrict__ x, const float* __restrict__ wq,
    const float* __restrict__ wv, unsigned short* __restrict__ xb,
    unsigned short* __restrict__ wqb, unsigned short* __restrict__ wvb) {
  int i = blockIdx.x * 256 + threadIdx.x;
  const float* src; unsigned short* dst; int off;
  if (i < 1048576) { src = x; dst = xb; off = i; }
  else if (i < 1310720) { src = wq; dst = wqb; off = i - 1048576; }
  else { src = wv; dst = wvb; off = i - 1310720; }
  float4 v = ((const float4*)src)[off];
  ushort4 o;
  o.x = f2bf(v.x); o.y = f2bf(v.y); o.z = f2bf(v.z); o.w = f2bf(v.w);
  ((ushort4*)dst)[off] = o;
}

// Merged GEMM: grid 512. Blocks [0,256) -> Q-proj (+RoPE) -> Kf.
// Blocks [256,512) -> V-proj -> Vf.  M=4096 N=1024 K=1024, bf16, f32 acc.
__global__ __launch_bounds__(256, 2) void qv_gemm(
    const unsigned short* __restrict__ A, const unsigned short* __restrict__ Wq,
    const unsigned short* __restrict__ Wv, const float* __restrict__ cosT,
    const float* __restrict__ sinT, unsigned short* __restrict__ Kf,
    unsigned short* __restrict__ Vf) {
  __shared__ unsigned short GS[2][2][128][64];  // [buf][A/B][row][col] 64KB
  int tid = threadIdx.x;
  int isq = blockIdx.x < 256;
  int b256 = blockIdx.x & 255;
  int bm = b256 & 31, bn = b256 >> 5;
  int w = tid >> 6, lane = tid & 63, lr = lane & 15, lg = lane >> 4;
  int wm = w >> 1, wn = w & 1;
  int l8 = lane >> 3, l7 = lane & 7;
  f32x4 acc[4][4] = {};

  const unsigned short* Wp = isq ? Wq : Wv;
  const unsigned short* srcbase =
      (w < 2) ? (A + bm * 128 * 1024) : (Wp + bn * 128 * 1024);
  int ab = w >> 1;

  auto stage = [&](int step) {
    int buf = step & 1, kt = step * 64;
#pragma unroll
    for (int i = 0; i < 8; ++i) {
      int rgrp = (w & 1) * 8 + i;
      int u = rgrp * 8 + l8;
      int ch = l7 ^ (u & 7);
      gload16(srcbase + u * 1024 + kt + ch * 8,
              (unsigned short*)&GS[buf][ab][rgrp * 8][0]);
    }
  };

  stage(0);
  for (int step = 0; step < 16; ++step) {
    int buf = step & 1;
    asm volatile("s_waitcnt vmcnt(0)" ::: "memory");
    __syncthreads();
    if (step + 1 < 16) stage(step + 1);
    s16x8 af[4][2], bfr[4][2];
#pragma unroll
    for (int mf = 0; mf < 4; ++mf)
#pragma unroll
      for (int kk = 0; kk < 2; ++kk)
        af[mf][kk] = *(const s16x8*)
            &GS[buf][0][wm * 64 + mf * 16 + lr][((kk * 4 + lg) ^ (lr & 7)) * 8];
#pragma unroll
    for (int nf = 0; nf < 4; ++nf)
#pragma unroll
      for (int kk = 0; kk < 2; ++kk)
        bfr[nf][kk] = *(const s16x8*)
            &GS[buf][1][wn * 64 + nf * 16 + lr][((kk * 4 + lg) ^ (lr & 7)) * 8];
#pragma unroll
    for (int mf = 0; mf < 4; ++mf)
#pragma unroll
      for (int nf = 0; nf < 4; ++nf)
#pragma unroll
        for (int kk = 0; kk < 2; ++kk)
          acc[mf][nf] = __builtin_amdgcn_mfma_f32_16x16x32_bf16(
              af[mf][kk], bfr[nf][kk], acc[mf][nf], 0, 0, 0);
  }

  int mBase = bm * 128 + wm * 64;
  int nBase = bn * 128 + wn * 64;
  if (isq) {
    // RoPE + write Kf in fragment order.
#pragma unroll
    for (int mf = 0; mf < 4; ++mf)
#pragma unroll
      for (int j = 0; j < 4; ++j) {
        int m = mBase + mf * 16 + 4 * lg + j;
        int b = m >> 11, s = m & 2047;
        int w64 = s & 63, kt = s >> 6;
        int nfk = ((w64 >> 5) << 1) | ((w64 >> 2) & 1);
        int r31 = w64 & 31;
        int lr2 = ((r31 >> 3) << 2) | (r31 & 3);
#pragma unroll
        for (int nf = 0; nf < 4; ++nf) {
          int col = nBase + nf * 16 + lr;
          int h = col >> 6, hd = col & 63;
          float self = acc[mf][nf][j];
          float part = (nf < 2) ? -acc[mf][nf + 2][j] : acc[mf][nf - 2][j];
          float val = self * cosT[s * 64 + hd] + part * sinT[s * 64 + hd];
          int bh = b * 16 + h;
          int kk = hd >> 5, lg2 = (hd >> 3) & 3, e = hd & 7;
          int idx = (((((bh * 32 + kt) * 4 + nfk) * 2 + kk) * 64) +
                     lg2 * 16 + lr2) * 8 + e;
          Kf[idx] = f2bf(val);
        }
      }
  } else {
    // Write Vf in fragment order; pack 4 j-values (consecutive e) per store.
#pragma unroll
    for (int mf = 0; mf < 4; ++mf) {
      int m0 = mBase + mf * 16 + 4 * lg;
      int b = m0 >> 11, s0 = m0 & 2047;
      int kt = s0 >> 6, w0 = s0 & 63;
      int kkv = w0 >> 5, lg2 = (w0 >> 3) & 3, e0 = w0 & 7;
#pragma unroll
      for (int nf = 0; nf < 4; ++nf) {
        int col = nBase + nf * 16 + lr;
        int h = col >> 6;
        int bh = b * 16 + h;
        ushort4 pk;
        pk.x = f2bf(acc[mf][nf][0]); pk.y = f2bf(acc[mf][nf][1]);
        pk.z = f2bf(acc[mf][nf][2]); pk.w = f2bf(acc[mf][nf][3]);
        int idx = (((((bh * 32 + kt) * 4 + nf) * 2 + kkv) * 64) +
                   lg2 * 16 + lr) * 8 + e0;
        *(ushort4*)&Vf[idx] = pk;
      }
    }
  }
}

// Flash attention: no LDS / no barriers in main loop. grid 1024,
// fid -> XCD-chunked bh, qt descending (LPT). 4 waves = (q-half, k-parity).
// Frag loads are coalesced 1KB dwordx4 from Kf/Vf. Pairwise merge via LDS.
__global__ __launch_bounds__(256, 2) void attn(
    const unsigned short* __restrict__ Kf,  // frag layout
    const unsigned short* __restrict__ Vf,  // frag layout
    float* __restrict__ out) {              // [2][2048][1024]
  __shared__ float MB[2][2][4][16][17];
  __shared__ float ML[2][2][2][16];
  const float SC = 0.125f * 1.44269504088896f;  // scale * log2(e)
  const float THR = 44.0f;                      // ~= 8 / SC
  int tid = threadIdx.x;
  int fid = blockIdx.x;
  int bh = 4 * (fid & 7) + ((fid >> 3) & 3);
  int qt = 31 - (fid >> 5);
  int w = tid >> 6, lane = tid & 63, lr = lane & 15, lg = lane >> 4;
  int q0 = qt * 64, qh = w >> 1, par = w & 1;

  const unsigned short* KfB = Kf + (size_t)bh * 32 * 4096;
  const unsigned short* VfB = Vf + (size_t)bh * 32 * 4096;

  // aq (B-operand) gathered from Kf once.
  s16x8 aq[2][2];
#pragma unroll
  for (int qs = 0; qs < 2; ++qs) {
    int qr = q0 + qh * 32 + 16 * qs + lr;
    int ktq = qr >> 6, w64 = qr & 63;
    int nfq = ((w64 >> 5) << 1) | ((w64 >> 2) & 1);
    int r31 = w64 & 31;
    int lr2 = ((r31 >> 3) << 2) | (r31 & 3);
#pragma unroll
    for (int kk = 0; kk < 2; ++kk)
      aq[qs][kk] = *(const s16x8*)
          &KfB[((((ktq * 4 + nfq) * 2 + kk) * 64) + lg * 16 + lr2) * 8];
  }

  f32x4 o[2][4] = {};
  float m_[2] = {-1e30f, -1e30f}, l_[2] = {0.f, 0.f};

  s16x8 kf[4][2], vf[4][2];
  auto loadK = [&](int kt) {
#pragma unroll
    for (int nf = 0; nf < 4; ++nf)
#pragma unroll
      for (int kk = 0; kk < 2; ++kk)
        kf[nf][kk] = *(const s16x8*)
            &KfB[(((kt * 4 + nf) * 2 + kk) * 64 + lane) * 8];
  };
  auto loadV = [&](int kt) {
#pragma unroll
    for (int nf = 0; nf < 4; ++nf)
#pragma unroll
      for (int kk = 0; kk < 2; ++kk)
        vf[nf][kk] = *(const s16x8*)
            &VfB[(((kt * 4 + nf) * 2 + kk) * 64 + lane) * 8];
  };

  int kt = par;
  bool active = kt <= qt;
  if (active) { loadK(kt); loadV(kt); }
  while (active) {
    // QK^T (swapped): sa[qs][nf][j] = S[kcol=kt*64+8lg+j+off(nf)][q0+qh*32+16qs+lr]
    f32x4 sa[2][4];
#pragma unroll
    for (int qs = 0; qs < 2; ++qs)
#pragma unroll
      for (int nf = 0; nf < 4; ++nf) sa[qs][nf] = (f32x4){0.f, 0.f, 0.f, 0.f};
#pragma unroll
    for (int kk = 0; kk < 2; ++kk)
#pragma unroll
      for (int nf = 0; nf < 4; ++nf)
#pragma unroll
        for (int qs = 0; qs < 2; ++qs)
          sa[qs][nf] = __builtin_amdgcn_mfma_f32_16x16x32_bf16(
              kf[nf][kk], aq[qs][kk], sa[qs][nf], 0, 0, 0);

    int ktn = kt + 2;
    bool more = ktn <= qt;
    if (more) loadK(ktn);  // pipelined: lands during softmax+PV

    if (kt == qt) {
#pragma unroll
      for (int qs = 0; qs < 2; ++qs) {
        int qglob = q0 + qh * 32 + 16 * qs + lr;
#pragma unroll
        for (int nf = 0; nf < 4; ++nf) {
          int kc = kt * 64 + 8 * lg + 4 * (nf & 1) + 32 * (nf >> 1);
#pragma unroll
          for (int j = 0; j < 4; ++j)
            if (kc + j > qglob) sa[qs][nf][j] = -3e38f;
        }
      }
    }
    float tm[2];
    float worst = -3e38f;
#pragma unroll
    for (int qs = 0; qs < 2; ++qs) {
      float t = sa[qs][0][0];
#pragma unroll
      for (int nf = 0; nf < 4; ++nf)
#pragma unroll
        for (int j = 0; j < 4; ++j) t = fmaxf(t, sa[qs][nf][j]);
      tm[qs] = t;
      worst = fmaxf(worst, t - m_[qs]);
    }
    if (!__all(worst <= THR)) {  // rare after first tile
#pragma unroll
      for (int qs = 0; qs < 2; ++qs) {
        float rm = fmaxf(tm[qs], __shfl_xor(tm[qs], 16));
        rm = fmaxf(rm, __shfl_xor(rm, 32));
        float mn = fmaxf(m_[qs], rm);
        float alpha = exp2f((m_[qs] - mn) * SC);
        m_[qs] = mn; l_[qs] *= alpha;
#pragma unroll
        for (int j = 0; j < 4; ++j) {
          float aj = __shfl(alpha, 4 * lg + j);
#pragma unroll
          for (int nf = 0; nf < 4; ++nf) o[qs][nf][j] *= aj;
        }
      }
    }
    unsigned cpk[2][8];
#pragma unroll
    for (int qs = 0; qs < 2; ++qs) {
      float msc = m_[qs] * SC;
#pragma unroll
      for (int nf = 0; nf < 4; ++nf) {
        float p0 = exp2f(fmaf(sa[qs][nf][0], SC, -msc));
        float p1 = exp2f(fmaf(sa[qs][nf][1], SC, -msc));
        float p2 = exp2f(fmaf(sa[qs][nf][2], SC, -msc));
        float p3 = exp2f(fmaf(sa[qs][nf][3], SC, -msc));
        l_[qs] += (p0 + p1) + (p2 + p3);
        unsigned r0, r1;
        asm("v_cvt_pk_bf16_f32 %0, %1, %2" : "=v"(r0) : "v"(p0), "v"(p1));
        asm("v_cvt_pk_bf16_f32 %0, %1, %2" : "=v"(r1) : "v"(p2), "v"(p3));
        cpk[qs][nf * 2] = r0; cpk[qs][nf * 2 + 1] = r1;
      }
    }
    s16x8 pav[2][2];
#pragma unroll
    for (int qs = 0; qs < 2; ++qs)
#pragma unroll
      for (int kk = 0; kk < 2; ++kk) {
        union { unsigned u[4]; s16x8 v; } pa;
        pa.u[0] = cpk[qs][4 * kk + 0]; pa.u[1] = cpk[qs][4 * kk + 1];
        pa.u[2] = cpk[qs][4 * kk + 2]; pa.u[3] = cpk[qs][4 * kk + 3];
        pav[qs][kk] = pa.v;
      }
#pragma unroll
    for (int kk = 0; kk < 2; ++kk)
#pragma unroll
      for (int nf = 0; nf < 4; ++nf)
#pragma unroll
        for (int qs = 0; qs < 2; ++qs)
          o[qs][nf] = __builtin_amdgcn_mfma_f32_16x16x32_bf16(
              pav[qs][kk], vf[nf][kk], o[qs][nf], 0, 0, 0);
    if (more) loadV(ktn);  // lands during next QK^T+softmax
    kt = ktn; active = more;
  }

  // pairwise merge: waves (qh,0) and (qh,1) share q-rows; odd writes, even merges
#pragma unroll
  for (int qs = 0; qs < 2; ++qs) {
    float t = l_[qs];
    t += __shfl_xor(t, 16); t += __shfl_xor(t, 32);
    l_[qs] = t;
  }
  if (par) {
#pragma unroll
    for (int qs = 0; qs < 2; ++qs) {
#pragma unroll
      for (int nf = 0; nf < 4; ++nf)
#pragma unroll
        for (int j = 0; j < 4; ++j)
          MB[qh][qs][nf][4 * lg + j][lr] = o[qs][nf][j];
      if (lg == 0) {
        ML[qh][qs][0][lr] = m_[qs];
        ML[qh][qs][1][lr] = l_[qs];
      }
    }
  }
  __syncthreads();
  if (!par) {
    int b = bh >> 4, h = bh & 15;
#pragma unroll
    for (int qs = 0; qs < 2; ++qs) {
      float m1 = ML[qh][qs][0][lr];
      float l1 = ML[qh][qs][1][lr];
      float ms = fmaxf(m_[qs], m1);
      float a0 = exp2f((m_[qs] - ms) * SC), a1 = exp2f((m1 - ms) * SC);
      float inv = 1.0f / (a0 * l_[qs] + a1 * l1);
#pragma unroll
      for (int j = 0; j < 4; ++j) {
        float c0 = __shfl(a0 * inv, 4 * lg + j);
        float c1 = __shfl(a1 * inv, 4 * lg + j);
#pragma unroll
        for (int nf = 0; nf < 4; ++nf) {
          float o1 = MB[qh][qs][nf][4 * lg + j][lr];
          int q = q0 + qh * 32 + 16 * qs + 4 * lg + j;
          out[(b * 2048 + q) * 1024 + h * 64 + nf * 16 + lr] =
              c0 * o[qs][nf][j] + c1 * o1;
        }
      }
    }
  }
}

extern "C" void kernel_launch(void* const* d_in, const int* in_sizes, int n_in,
                              void* d_out, int out_size, void* d_ws, size_t ws_size,
                              hipStream_t stream) {
  const float* x = (const float*)d_in[0];
  const float* Wq = (const float*)d_in[1];
  const float* Wv = (const float*)d_in[2];
  const float* cosT = (const float*)d_in[3];
  const float* sinT = (const float*)d_in[4];
  float* out = (float*)d_out;

  unsigned short* xb = (unsigned short*)d_ws;        // 4M shorts
  unsigned short* wqb = xb + 4 * 1024 * 1024;        // 1M
  unsigned short* wvb = wqb + 1024 * 1024;           // 1M
  unsigned short* Kfb = wvb + 1024 * 1024;           // 4M (frag-layout RoPE'd Q==K)
  unsigned short* Vfb = Kfb + 4 * 1024 * 1024;       // 4M (frag-layout V)

  convert_all<<<6144, 256, 0, stream>>>(x, Wq, Wv, xb, wqb, wvb);
  qv_gemm<<<512, 256, 0, stream>>>(xb, wqb, wvb, cosT, sinT, Kfb, Vfb);
  attn<<<1024, 256, 0, stream>>>(Kfb, Vfb, out);
}

// Round 7
// 66.091 us; speedup vs baseline: 2.1022x; 1.0029x over previous
//
#include <hip/hip_runtime.h>

// B=2, S=2048, D=1024, H=16, HD=64. K == Q (xk = x@Wq.T, same RoPE).
// Pipeline: fused f32->bf16 convert -> one merged GEMM kernel:
//   [x@Wq.T + RoPE -> Kf frag-layout], [x@Wv.T -> Vf frag-layout]
// -> flash attention with NO LDS staging / NO barriers in the main loop:
//   K/V fragments stored in exact MFMA-fragment order; frag loads are
//   fully-coalesced global_load_dwordx4 (base + lane*16B), L2-resident.
// Frag layout: F[bh][kt][nf][kk][lane][8 shorts];
//   Kf[...][lane=(lg,lr)] = K[kt*64 + crow(lr) + 4(nf&1) + 32(nf>>1)][kk*32+lg*8..]
//   Vf[...][lane=(lg,lr)] = V[kt*64 + kk*32 + lg*8..][16nf + lr]   (V^T frags)
// crow(lr) = 8*(lr>>2)+(lr&3): makes swapped-QK^T output land in PV-A order.
// R7: Kf epilogue now goes through a per-wave LDS transpose so stores are
//     8x coalesced dwordx4 per thread instead of 64 scattered 2B stores.

typedef float f32x4 __attribute__((ext_vector_type(4)));
typedef short s16x8 __attribute__((ext_vector_type(8)));

__device__ inline unsigned short f2bf(float f) {
  union { float f; unsigned u; } v; v.f = f;
  unsigned r = v.u + 0x7FFFu + ((v.u >> 16) & 1u);
  return (unsigned short)(r >> 16);
}

__device__ inline void gload16(const unsigned short* g, unsigned short* l) {
  __builtin_amdgcn_global_load_lds(
      (const __attribute__((address_space(1))) unsigned int*)g,
      (__attribute__((address_space(3))) unsigned int*)l, 16, 0, 0);
}

__global__ __launch_bounds__(256) void convert_all(
    const float* __restrict__ x, const float* __restrict__ wq,
    const float* __restrict__ wv, unsigned short* __restrict__ xb,
    unsigned short* __restrict__ wqb, unsigned short* __restrict__ wvb) {
  int i = blockIdx.x * 256 + threadIdx.x;
  const float* src; unsigned short* dst; int off;
  if (i < 1048576) { src = x; dst = xb; off = i; }
  else if (i < 1310720) { src = wq; dst = wqb; off = i - 1048576; }
  else { src = wv; dst = wvb; off = i - 1310720; }
  float4 v = ((const float4*)src)[off];
  ushort4 o;
  o.x = f2bf(v.x); o.y = f2bf(v.y); o.z = f2bf(v.z); o.w = f2bf(v.w);
  ((ushort4*)dst)[off] = o;
}

// Merged GEMM: grid 512. Blocks [0,256) -> Q-proj (+RoPE) -> Kf.
// Blocks [256,512) -> V-proj -> Vf.  M=4096 N=1024 K=1024, bf16, f32 acc.
__global__ __launch_bounds__(256, 2) void qv_gemm(
    const unsigned short* __restrict__ A, const unsigned short* __restrict__ Wq,
    const unsigned short* __restrict__ Wv, const float* __restrict__ cosT,
    const float* __restrict__ sinT, unsigned short* __restrict__ Kf,
    unsigned short* __restrict__ Vf) {
  __shared__ unsigned short GS[2][2][128][64];  // [buf][A/B][row][col] 64KB
  int tid = threadIdx.x;
  int isq = blockIdx.x < 256;
  int b256 = blockIdx.x & 255;
  int bm = b256 & 31, bn = b256 >> 5;
  int w = tid >> 6, lane = tid & 63, lr = lane & 15, lg = lane >> 4;
  int wm = w >> 1, wn = w & 1;
  int l8 = lane >> 3, l7 = lane & 7;
  f32x4 acc[4][4] = {};

  const unsigned short* Wp = isq ? Wq : Wv;
  const unsigned short* srcbase =
      (w < 2) ? (A + bm * 128 * 1024) : (Wp + bn * 128 * 1024);
  int ab = w >> 1;

  auto stage = [&](int step) {
    int buf = step & 1, kt = step * 64;
#pragma unroll
    for (int i = 0; i < 8; ++i) {
      int rgrp = (w & 1) * 8 + i;
      int u = rgrp * 8 + l8;
      int ch = l7 ^ (u & 7);
      gload16(srcbase + u * 1024 + kt + ch * 8,
              (unsigned short*)&GS[buf][ab][rgrp * 8][0]);
    }
  };

  stage(0);
  for (int step = 0; step < 16; ++step) {
    int buf = step & 1;
    asm volatile("s_waitcnt vmcnt(0)" ::: "memory");
    __syncthreads();
    if (step + 1 < 16) stage(step + 1);
    s16x8 af[4][2], bfr[4][2];
#pragma unroll
    for (int mf = 0; mf < 4; ++mf)
#pragma unroll
      for (int kk = 0; kk < 2; ++kk)
        af[mf][kk] = *(const s16x8*)
            &GS[buf][0][wm * 64 + mf * 16 + lr][((kk * 4 + lg) ^ (lr & 7)) * 8];
#pragma unroll
    for (int nf = 0; nf < 4; ++nf)
#pragma unroll
      for (int kk = 0; kk < 2; ++kk)
        bfr[nf][kk] = *(const s16x8*)
            &GS[buf][1][wn * 64 + nf * 16 + lr][((kk * 4 + lg) ^ (lr & 7)) * 8];
#pragma unroll
    for (int mf = 0; mf < 4; ++mf)
#pragma unroll
      for (int nf = 0; nf < 4; ++nf)
#pragma unroll
        for (int kk = 0; kk < 2; ++kk)
          acc[mf][nf] = __builtin_amdgcn_mfma_f32_16x16x32_bf16(
              af[mf][kk], bfr[nf][kk], acc[mf][nf], 0, 0, 0);
  }

  int mBase = bm * 128 + wm * 64;
  int nBase = bn * 128 + wn * 64;
  if (isq) {
    // RoPE, then per-wave LDS transpose -> coalesced dwordx4 Kf stores.
    // Wave's 64 s-rows = one kt tile; 64 cols = one head.
    __syncthreads();  // all waves done reading GS staging
    unsigned short* Lw = &GS[0][0][0][0] + w * (64 * 72);
    int wavebase = mBase;
    int bq = wavebase >> 11;
    int sbase = wavebase & 2047;
    int kt = sbase >> 6;
    int h = (nBase >> 6);          // bn*2 + wn
    int bh = bq * 16 + h;
#pragma unroll
    for (int mf = 0; mf < 4; ++mf)
#pragma unroll
      for (int j = 0; j < 4; ++j) {
        int sp = mf * 16 + 4 * lg + j;
        int s = sbase + sp;
#pragma unroll
        for (int nf = 0; nf < 4; ++nf) {
          int hd = nf * 16 + lr;
          float self = acc[mf][nf][j];
          float part = (nf < 2) ? -acc[mf][nf + 2][j] : acc[mf][nf - 2][j];
          float val = self * cosT[s * 64 + hd] + part * sinT[s * 64 + hd];
          Lw[sp * 72 + hd] = f2bf(val);
        }
      }
    asm volatile("s_waitcnt lgkmcnt(0)" ::: "memory");
    __builtin_amdgcn_sched_barrier(0);
    unsigned short* KfT = Kf + (size_t)(bh * 32 + kt) * 4096;
#pragma unroll
    for (int i = 0; i < 8; ++i) {
      int kk = i & 1, nfk = i >> 1;
      int lg2 = lane >> 4, lr2 = lane & 15;
      int sp = ((nfk >> 1) << 5) | ((lr2 >> 2) << 3) | ((nfk & 1) << 2) |
               (lr2 & 3);
      int c = kk * 4 + lg2;
      s16x8 vch = *(const s16x8*)&Lw[sp * 72 + c * 8];
      *(s16x8*)&KfT[(i * 64 + lane) * 8] = vch;
    }
  } else {
    // Vf frag order; 8B stores (verified: one instr covers 512B contiguous).
#pragma unroll
    for (int mf = 0; mf < 4; ++mf) {
      int m0 = mBase + mf * 16 + 4 * lg;
      int b = m0 >> 11, s0 = m0 & 2047;
      int kt = s0 >> 6, w0 = s0 & 63;
      int kkv = w0 >> 5, lg2 = (w0 >> 3) & 3, e0 = w0 & 7;
#pragma unroll
      for (int nf = 0; nf < 4; ++nf) {
        int col = nBase + nf * 16 + lr;
        int h = col >> 6;
        int bh = b * 16 + h;
        ushort4 pk;
        pk.x = f2bf(acc[mf][nf][0]); pk.y = f2bf(acc[mf][nf][1]);
        pk.z = f2bf(acc[mf][nf][2]); pk.w = f2bf(acc[mf][nf][3]);
        int idx = (((((bh * 32 + kt) * 4 + nf) * 2 + kkv) * 64) +
                   lg2 * 16 + lr) * 8 + e0;
        *(ushort4*)&Vf[idx] = pk;
      }
    }
  }
}

// Flash attention: no LDS / no barriers in main loop. grid 1024,
// fid -> XCD-chunked bh, qt descending (LPT). 4 waves = (q-half, k-parity).
// Frag loads are coalesced 1KB dwordx4 from Kf/Vf. Pairwise merge via LDS.
__global__ __launch_bounds__(256, 2) void attn(
    const unsigned short* __restrict__ Kf,  // frag layout
    const unsigned short* __restrict__ Vf,  // frag layout
    float* __restrict__ out) {              // [2][2048][1024]
  __shared__ float MB[2][2][4][16][17];
  __shared__ float ML[2][2][2][16];
  const float SC = 0.125f * 1.44269504088896f;  // scale * log2(e)
  const float THR = 44.0f;                      // ~= 8 / SC
  int tid = threadIdx.x;
  int fid = blockIdx.x;
  int bh = 4 * (fid & 7) + ((fid >> 3) & 3);
  int qt = 31 - (fid >> 5);
  int w = tid >> 6, lane = tid & 63, lr = lane & 15, lg = lane >> 4;
  int q0 = qt * 64, qh = w >> 1, par = w & 1;

  const unsigned short* KfB = Kf + (size_t)bh * 32 * 4096;
  const unsigned short* VfB = Vf + (size_t)bh * 32 * 4096;

  // aq (B-operand) gathered from Kf once.
  s16x8 aq[2][2];
#pragma unroll
  for (int qs = 0; qs < 2; ++qs) {
    int qr = q0 + qh * 32 + 16 * qs + lr;
    int ktq = qr >> 6, w64 = qr & 63;
    int nfq = ((w64 >> 5) << 1) | ((w64 >> 2) & 1);
    int r31 = w64 & 31;
    int lr2 = ((r31 >> 3) << 2) | (r31 & 3);
#pragma unroll
    for (int kk = 0; kk < 2; ++kk)
      aq[qs][kk] = *(const s16x8*)
          &KfB[((((ktq * 4 + nfq) * 2 + kk) * 64) + lg * 16 + lr2) * 8];
  }

  f32x4 o[2][4] = {};
  float m_[2] = {-1e30f, -1e30f}, l_[2] = {0.f, 0.f};

  s16x8 kf[4][2], vf[4][2];
  auto loadK = [&](int kt) {
#pragma unroll
    for (int nf = 0; nf < 4; ++nf)
#pragma unroll
      for (int kk = 0; kk < 2; ++kk)
        kf[nf][kk] = *(const s16x8*)
            &KfB[(((kt * 4 + nf) * 2 + kk) * 64 + lane) * 8];
  };
  auto loadV = [&](int kt) {
#pragma unroll
    for (int nf = 0; nf < 4; ++nf)
#pragma unroll
      for (int kk = 0; kk < 2; ++kk)
        vf[nf][kk] = *(const s16x8*)
            &VfB[(((kt * 4 + nf) * 2 + kk) * 64 + lane) * 8];
  };

  int kt = par;
  bool active = kt <= qt;
  if (active) { loadK(kt); loadV(kt); }
  while (active) {
    // QK^T (swapped): sa[qs][nf][j] = S[kcol=kt*64+8lg+j+off(nf)][q0+qh*32+16qs+lr]
    f32x4 sa[2][4];
#pragma unroll
    for (int qs = 0; qs < 2; ++qs)
#pragma unroll
      for (int nf = 0; nf < 4; ++nf) sa[qs][nf] = (f32x4){0.f, 0.f, 0.f, 0.f};
#pragma unroll
    for (int kk = 0; kk < 2; ++kk)
#pragma unroll
      for (int nf = 0; nf < 4; ++nf)
#pragma unroll
        for (int qs = 0; qs < 2; ++qs)
          sa[qs][nf] = __builtin_amdgcn_mfma_f32_16x16x32_bf16(
              kf[nf][kk], aq[qs][kk], sa[qs][nf], 0, 0, 0);

    int ktn = kt + 2;
    bool more = ktn <= qt;
    if (more) loadK(ktn);  // pipelined: lands during softmax+PV

    if (kt == qt) {
#pragma unroll
      for (int qs = 0; qs < 2; ++qs) {
        int qglob = q0 + qh * 32 + 16 * qs + lr;
#pragma unroll
        for (int nf = 0; nf < 4; ++nf) {
          int kc = kt * 64 + 8 * lg + 4 * (nf & 1) + 32 * (nf >> 1);
#pragma unroll
          for (int j = 0; j < 4; ++j)
            if (kc + j > qglob) sa[qs][nf][j] = -3e38f;
        }
      }
    }
    float tm[2];
    float worst = -3e38f;
#pragma unroll
    for (int qs = 0; qs < 2; ++qs) {
      float t = sa[qs][0][0];
#pragma unroll
      for (int nf = 0; nf < 4; ++nf)
#pragma unroll
        for (int j = 0; j < 4; ++j) t = fmaxf(t, sa[qs][nf][j]);
      tm[qs] = t;
      worst = fmaxf(worst, t - m_[qs]);
    }
    if (!__all(worst <= THR)) {  // rare after first tile
#pragma unroll
      for (int qs = 0; qs < 2; ++qs) {
        float rm = fmaxf(tm[qs], __shfl_xor(tm[qs], 16));
        rm = fmaxf(rm, __shfl_xor(rm, 32));
        float mn = fmaxf(m_[qs], rm);
        float alpha = exp2f((m_[qs] - mn) * SC);
        m_[qs] = mn; l_[qs] *= alpha;
#pragma unroll
        for (int j = 0; j < 4; ++j) {
          float aj = __shfl(alpha, 4 * lg + j);
#pragma unroll
          for (int nf = 0; nf < 4; ++nf) o[qs][nf][j] *= aj;
        }
      }
    }
    unsigned cpk[2][8];
#pragma unroll
    for (int qs = 0; qs < 2; ++qs) {
      float msc = m_[qs] * SC;
#pragma unroll
      for (int nf = 0; nf < 4; ++nf) {
        float p0 = exp2f(fmaf(sa[qs][nf][0], SC, -msc));
        float p1 = exp2f(fmaf(sa[qs][nf][1], SC, -msc));
        float p2 = exp2f(fmaf(sa[qs][nf][2], SC, -msc));
        float p3 = exp2f(fmaf(sa[qs][nf][3], SC, -msc));
        l_[qs] += (p0 + p1) + (p2 + p3);
        unsigned r0, r1;
        asm("v_cvt_pk_bf16_f32 %0, %1, %2" : "=v"(r0) : "v"(p0), "v"(p1));
        asm("v_cvt_pk_bf16_f32 %0, %1, %2" : "=v"(r1) : "v"(p2), "v"(p3));
        cpk[qs][nf * 2] = r0; cpk[qs][nf * 2 + 1] = r1;
      }
    }
    s16x8 pav[2][2];
#pragma unroll
    for (int qs = 0; qs < 2; ++qs)
#pragma unroll
      for (int kk = 0; kk < 2; ++kk) {
        union { unsigned u[4]; s16x8 v; } pa;
        pa.u[0] = cpk[qs][4 * kk + 0]; pa.u[1] = cpk[qs][4 * kk + 1];
        pa.u[2] = cpk[qs][4 * kk + 2]; pa.u[3] = cpk[qs][4 * kk + 3];
        pav[qs][kk] = pa.v;
      }
#pragma unroll
    for (int kk = 0; kk < 2; ++kk)
#pragma unroll
      for (int nf = 0; nf < 4; ++nf)
#pragma unroll
        for (int qs = 0; qs < 2; ++qs)
          o[qs][nf] = __builtin_amdgcn_mfma_f32_16x16x32_bf16(
              pav[qs][kk], vf[nf][kk], o[qs][nf], 0, 0, 0);
    if (more) loadV(ktn);  // lands during next QK^T+softmax
    kt = ktn; active = more;
  }

  // pairwise merge: waves (qh,0) and (qh,1) share q-rows; odd writes, even merges
#pragma unroll
  for (int qs = 0; qs < 2; ++qs) {
    float t = l_[qs];
    t += __shfl_xor(t, 16); t += __shfl_xor(t, 32);
    l_[qs] = t;
  }
  if (par) {
#pragma unroll
    for (int qs = 0; qs < 2; ++qs) {
#pragma unroll
      for (int nf = 0; nf < 4; ++nf)
#pragma unroll
        for (int j = 0; j < 4; ++j)
          MB[qh][qs][nf][4 * lg + j][lr] = o[qs][nf][j];
      if (lg == 0) {
        ML[qh][qs][0][lr] = m_[qs];
        ML[qh][qs][1][lr] = l_[qs];
      }
    }
  }
  __syncthreads();
  if (!par) {
    int b = bh >> 4, h = bh & 15;
#pragma unroll
    for (int qs = 0; qs < 2; ++qs) {
      float m1 = ML[qh][qs][0][lr];
      float l1 = ML[qh][qs][1][lr];
      float ms = fmaxf(m_[qs], m1);
      float a0 = exp2f((m_[qs] - ms) * SC), a1 = exp2f((m1 - ms) * SC);
      float inv = 1.0f / (a0 * l_[qs] + a1 * l1);
#pragma unroll
      for (int j = 0; j < 4; ++j) {
        float c0 = __shfl(a0 * inv, 4 * lg + j);
        float c1 = __shfl(a1 * inv, 4 * lg + j);
#pragma unroll
        for (int nf = 0; nf < 4; ++nf) {
          float o1 = MB[qh][qs][nf][4 * lg + j][lr];
          int q = q0 + qh * 32 + 16 * qs + 4 * lg + j;
          out[(b * 2048 + q) * 1024 + h * 64 + nf * 16 + lr] =
              c0 * o[qs][nf][j] + c1 * o1;
        }
      }
    }
  }
}

extern "C" void kernel_launch(void* const* d_in, const int* in_sizes, int n_in,
                              void* d_out, int out_size, void* d_ws, size_t ws_size,
                              hipStream_t stream) {
  const float* x = (const float*)d_in[0];
  const float* Wq = (const float*)d_in[1];
  const float* Wv = (const float*)d_in[2];
  const float* cosT = (const float*)d_in[3];
  const float* sinT = (const float*)d_in[4];
  float* out = (float*)d_out;

  unsigned short* xb = (unsigned short*)d_ws;        // 4M shorts
  unsigned short* wqb = xb + 4 * 1024 * 1024;        // 1M
  unsigned short* wvb = wqb + 1024 * 1024;           // 1M
  unsigned short* Kfb = wvb + 1024 * 1024;           // 4M (frag-layout RoPE'd Q==K)
  unsigned short* Vfb = Kfb + 4 * 1024 * 1024;       // 4M (frag-layout V)

  convert_all<<<6144, 256, 0, stream>>>(x, Wq, Wv, xb, wqb, wvb);
  qv_gemm<<<512, 256, 0, stream>>>(xb, wqb, wvb, cosT, sinT, Kfb, Vfb);
  attn<<<1024, 256, 0, stream>>>(Kfb, Vfb, out);
}